// Round 4
// baseline (204.648 us; speedup 1.0000x reference)
//
#include <hip/hip_runtime.h>

#define N_NODES 16384
#define FIN     256
#define FOUT    64
#define MAXW    512    // neighbor cap per row: mean ~32, sigma ~5.7 -> 84 sigma

typedef float f32x4 __attribute__((ext_vector_type(4)));

// ---------------- Kernel 1: support = x @ weight  [N,FIN]@[FIN,FOUT] ----------
__global__ __launch_bounds__(256) void support_gemm(
    const float* __restrict__ x, const float* __restrict__ w,
    float* __restrict__ support) {
  __shared__ float wl[FIN * FOUT];   // 64 KB  [k][c]
  __shared__ float xl[16][FIN];      // 16 KB  [r][k]
  const int t = threadIdx.x;

  const float4* w4 = (const float4*)w;
  float4* wl4 = (float4*)wl;
#pragma unroll
  for (int i = 0; i < 16; ++i) wl4[i * 256 + t] = w4[i * 256 + t];

  const int row0 = blockIdx.x * 16;
  const float4* x4 = (const float4*)(x + (size_t)row0 * FIN);
  float4* xl4 = (float4*)xl;
#pragma unroll
  for (int i = 0; i < 4; ++i) xl4[i * 256 + t] = x4[i * 256 + t];
  __syncthreads();

  const int wv = t >> 6;        // wave id 0..3
  const int c  = t & 63;        // output column
  const int r0 = wv * 4;        // this wave's 4 rows
  float acc0 = 0.f, acc1 = 0.f, acc2 = 0.f, acc3 = 0.f;

#pragma unroll 4
  for (int k = 0; k < FIN; k += 4) {
    const f32x4 xv0 = *(const f32x4*)&xl[r0 + 0][k];
    const f32x4 xv1 = *(const f32x4*)&xl[r0 + 1][k];
    const f32x4 xv2 = *(const f32x4*)&xl[r0 + 2][k];
    const f32x4 xv3 = *(const f32x4*)&xl[r0 + 3][k];
    const float w0 = wl[(k + 0) * FOUT + c];
    const float w1 = wl[(k + 1) * FOUT + c];
    const float w2 = wl[(k + 2) * FOUT + c];
    const float w3 = wl[(k + 3) * FOUT + c];
    acc0 += xv0[0] * w0 + xv0[1] * w1 + xv0[2] * w2 + xv0[3] * w3;
    acc1 += xv1[0] * w0 + xv1[1] * w1 + xv1[2] * w2 + xv1[3] * w3;
    acc2 += xv2[0] * w0 + xv2[1] * w1 + xv2[2] * w2 + xv2[3] * w3;
    acc3 += xv3[0] * w0 + xv3[1] * w1 + xv3[2] * w2 + xv3[3] * w3;
  }
  float* outp = support + (size_t)(row0 + r0) * FOUT + c;
  outp[0 * FOUT] = acc0;
  outp[1 * FOUT] = acc1;
  outp[2 * FOUT] = acc2;
  outp[3 * FOUT] = acc3;
}

// ---------------- Kernel 2: sparse mean-aggregate + bias ----------------------
// WAVE-per-row, barrier-free, gathers interleaved between stream batches.
// Per batch h: (1) gather support rows for neighbors found in batches < h
//   (these vmem loads are OLDER than batch h's stream loads, so consuming
//   them never drains the stream — in-order vmcnt), (2) issue 8 nontemporal
//   float4 stream loads, (3) test + compact nonzeros into per-wave LDS.
// Only a ~4-element tail gather remains after the last batch, so no
// synchronized memory-idle phase at row end.
__global__ __launch_bounds__(256, 6) void aggregate(
    const float* __restrict__ adj, const float* __restrict__ support,
    const float* __restrict__ bias, float* __restrict__ out) {
  __shared__ int nbr[4][MAXW];
  __shared__ int cnt[4];

  const int t    = threadIdx.x;
  const int wv   = t >> 6;
  const int lane = t & 63;
  const int row  = blockIdx.x * 4 + wv;

  if (lane == 0) cnt[wv] = 0;   // wave-lockstep: ordered before this wave's atomics

  const f32x4* a4  = (const f32x4*)(adj + (size_t)row * N_NODES);
  const float* sup = support + lane;

  float s0 = 0.f, s1 = 0.f, s2 = 0.f, s3 = 0.f;
  int   c0 = 0, c1 = 0, c2 = 0, c3 = 0;
  int done = 0;

#pragma unroll 1
  for (int h = 0; h < 8; ++h) {
    // (1) gather neighbors discovered so far
    const int m = min(cnt[wv], MAXW);
    int n = done;
    for (; n + 4 <= m; n += 4) {
      const float v0 = sup[(size_t)nbr[wv][n + 0] * FOUT];
      const float v1 = sup[(size_t)nbr[wv][n + 1] * FOUT];
      const float v2 = sup[(size_t)nbr[wv][n + 2] * FOUT];
      const float v3 = sup[(size_t)nbr[wv][n + 3] * FOUT];
      s0 += v0; c0 += (v0 != 0.f);
      s1 += v1; c1 += (v1 != 0.f);
      s2 += v2; c2 += (v2 != 0.f);
      s3 += v3; c3 += (v3 != 0.f);
    }
    for (; n < m; ++n) {
      const float v = sup[(size_t)nbr[wv][n] * FOUT];
      s0 += v; c0 += (v != 0.f);
    }
    done = m;

    // (2) issue this batch's 8 stream loads back-to-back
    f32x4 av[8];
#pragma unroll
    for (int j = 0; j < 8; ++j)
      av[j] = __builtin_nontemporal_load(&a4[h * 512 + j * 64 + lane]);

    // (3) test + compact
#pragma unroll
    for (int j = 0; j < 8; ++j) {
      const f32x4 a = av[j];
      const int nz = (a[0] != 0.f) + (a[1] != 0.f) + (a[2] != 0.f) + (a[3] != 0.f);
      if (nz) {
        int p = atomicAdd(&cnt[wv], nz);
        if (p + nz <= MAXW) {
          const int kbase = (h * 512 + j * 64 + lane) * 4;
          if (a[0] != 0.f) nbr[wv][p++] = kbase;
          if (a[1] != 0.f) nbr[wv][p++] = kbase + 1;
          if (a[2] != 0.f) nbr[wv][p++] = kbase + 2;
          if (a[3] != 0.f) nbr[wv][p++] = kbase + 3;
        }
      }
    }
  }

  // tail gather (last batch's finds, ~4 entries)
  const int m = min(cnt[wv], MAXW);
  int n = done;
  for (; n + 4 <= m; n += 4) {
    const float v0 = sup[(size_t)nbr[wv][n + 0] * FOUT];
    const float v1 = sup[(size_t)nbr[wv][n + 1] * FOUT];
    const float v2 = sup[(size_t)nbr[wv][n + 2] * FOUT];
    const float v3 = sup[(size_t)nbr[wv][n + 3] * FOUT];
    s0 += v0; c0 += (v0 != 0.f);
    s1 += v1; c1 += (v1 != 0.f);
    s2 += v2; c2 += (v2 != 0.f);
    s3 += v3; c3 += (v3 != 0.f);
  }
  for (; n < m; ++n) {
    const float v = sup[(size_t)nbr[wv][n] * FOUT];
    s0 += v; c0 += (v != 0.f);
  }

  const float s = (s0 + s1) + (s2 + s3);
  const int   c = (c0 + c1) + (c2 + c3);
  out[(size_t)row * FOUT + lane] = s / (float)c + bias[lane];
}

extern "C" void kernel_launch(void* const* d_in, const int* in_sizes, int n_in,
                              void* d_out, int out_size, void* d_ws, size_t ws_size,
                              hipStream_t stream) {
  const float* x    = (const float*)d_in[0];
  const float* adj  = (const float*)d_in[1];
  const float* w    = (const float*)d_in[2];
  const float* bias = (const float*)d_in[3];
  float* out = (float*)d_out;
  float* support = (float*)d_ws;   // 4 MB scratch

  support_gemm<<<N_NODES / 16, 256, 0, stream>>>(x, w, support);
  aggregate<<<N_NODES / 4, 256, 0, stream>>>(adj, support, bias, out);
}